// Round 9
// baseline (201.479 us; speedup 1.0000x reference)
//
#include <hip/hip_runtime.h>
#include <hip/hip_bf16.h>

#define NROWS 8192
#define KD    1024

typedef __attribute__((ext_vector_type(8))) short bf16x8;
typedef __attribute__((ext_vector_type(4))) float f32x4;

__device__ unsigned short g_x1n[(size_t)NROWS * KD];
__device__ unsigned short g_x2n[(size_t)NROWS * KD];

__device__ __forceinline__ unsigned short f2bf(float f) {
    union { float f; unsigned u; } x; x.f = f;
    return (unsigned short)((x.u + 0x7fffu + ((x.u >> 16) & 1u)) >> 16);  // RNE
}

__global__ __launch_bounds__(256) void norm_cast_kernel(const float* __restrict__ x1,
                                                        const float* __restrict__ x2) {
    int row = blockIdx.x;
    const float* src;
    unsigned short* dst;
    if (row < NROWS) { src = x1 + (size_t)row * KD;           dst = g_x1n + (size_t)row * KD; }
    else             { src = x2 + (size_t)(row - NROWS) * KD; dst = g_x2n + (size_t)(row - NROWS) * KD; }

    int t = threadIdx.x;
    float4 v = ((const float4*)src)[t];
    float s = v.x * v.x + v.y * v.y + v.z * v.z + v.w * v.w;
    #pragma unroll
    for (int off = 32; off > 0; off >>= 1) s += __shfl_down(s, off);

    __shared__ float red[4];
    if ((t & 63) == 0) red[t >> 6] = s;
    __syncthreads();
    float tot = red[0] + red[1] + red[2] + red[3];
    float inv = 1.0f / fmaxf(sqrtf(tot), 1e-8f);

    ushort4 o;
    o.x = f2bf(v.x * inv); o.y = f2bf(v.y * inv);
    o.z = f2bf(v.z * inv); o.w = f2bf(v.w * inv);
    ((ushort4*)dst)[t] = o;
}

__device__ __forceinline__ void gload_lds16(const unsigned short* g, unsigned short* l) {
    __builtin_amdgcn_global_load_lds((const __attribute__((address_space(1))) void*)g,
                                     (__attribute__((address_space(3))) void*)l,
                                     16, 0, 0);
}

#define BARX() do { asm volatile("" ::: "memory"); __builtin_amdgcn_s_barrier(); \
                    asm volatile("" ::: "memory"); } while (0)
#define MFMA16(a, b, c) __builtin_amdgcn_mfma_f32_16x16x32_bf16((a), (b), (c), 0, 0, 0)

struct Ctx {
    const unsigned short* srcA;   // advancing: next tile's k-col (incl. trow*KD + scol)
    const unsigned short* srcB;
    unsigned short* ldsf;
    int ldst;                     // t*8
    int aoff0, aoff1, boff0, boff1;
};

// Stage one full 128x64 panel: 4 x global_load_lds(16B) per thread (256 threads).
__device__ __forceinline__ void stage_panel(Ctx& c, bool isA, int region) {
    const unsigned short* src = isA ? c.srcA : c.srcB;
    unsigned short* dst = c.ldsf + region * 8192 + c.ldst;
    #pragma unroll
    for (int i = 0; i < 4; ++i)
        gload_lds16(src + (size_t)(i * 32) * KD, dst + i * 2048);
}

// One K-tile (BK=64): stage T+1 into buf^1, then 16 ds_reads + 32 MFMA
// (compiler-interleaved, fine lgkmcnt), then vmcnt(0)+lgkm(0)+barrier.
// Cross-BLOCK overlap (2 independent barrier domains/CU) hides the bursts.
template<int BUF, bool SN>
__device__ __forceinline__ void tile_body(Ctx& c, f32x4 (&acc)[4][4]) {
    if (SN) {
        stage_panel(c, true,  (BUF ^ 1) * 2 + 0);
        stage_panel(c, false, (BUF ^ 1) * 2 + 1);
        c.srcA += 64; c.srcB += 64;
    }
    __builtin_amdgcn_sched_barrier(0);   // pin stage issue at tile top

    const unsigned short* ab = c.ldsf + (BUF * 2 + 0) * 8192;
    const unsigned short* bb = c.ldsf + (BUF * 2 + 1) * 8192;

    bf16x8 B[4][2];
    #pragma unroll
    for (int ni = 0; ni < 4; ++ni) {
        B[ni][0] = *(const bf16x8*)(bb + ni * 1024 + c.boff0);
        B[ni][1] = *(const bf16x8*)(bb + ni * 1024 + c.boff1);
    }
    #pragma unroll
    for (int mi = 0; mi < 4; ++mi) {
        bf16x8 a0 = *(const bf16x8*)(ab + mi * 1024 + c.aoff0);
        bf16x8 a1 = *(const bf16x8*)(ab + mi * 1024 + c.aoff1);
        #pragma unroll
        for (int ni = 0; ni < 4; ++ni) {
            acc[mi][ni] = MFMA16(a0, B[ni][0], acc[mi][ni]);
            acc[mi][ni] = MFMA16(a1, B[ni][1], acc[mi][ni]);
        }
    }

    asm volatile("s_waitcnt vmcnt(0) lgkmcnt(0)" ::: "memory");
    BARX();                               // publish T+1; close T reads
}

// 128x128 tile, BK=64, 4 waves (2x2), double-buffered 64KiB LDS -> 2 blocks/CU.
__global__ __launch_bounds__(256, 2) void gemm128_kernel(float* __restrict__ C) {
    __shared__ unsigned short lds[2][2][8192];   // 64 KiB

    // XCD map: bn-band pinned per XCD (B 8x128-row panels = 2MB L2-resident
    // across all 8 rounds); A rectangle streams. Bijective: 4096 blocks.
    int bid = blockIdx.x;
    int xcd = bid & 7;
    int idx = bid >> 3;                   // 0..511
    int rnd = idx >> 6;                   // 0..7
    int j   = idx & 63;                   // 0..63
    int bm = rnd * 8 + (j >> 3);          // 0..63
    int bn = xcd * 8 + (j & 7);           // 0..63 (fixed band per XCD)

    int t = threadIdx.x;
    int lane = t & 63, wid = t >> 6;
    int wr = wid >> 1, wc = wid & 1;
    int r = lane & 15;
    int s0 = (lane >> 4) ^ (r & 7);       // swizzled 16B slot, kk=0
    int s1 = s0 ^ 4;                      // kk=1

    Ctx c;
    {
        int trow = t >> 3;                // 0..31
        int scol = ((t & 7) ^ (trow & 7)) * 8;   // inverse swizzle on global source
        c.srcA = g_x1n + (size_t)bm * 128 * KD + (size_t)trow * KD + scol;
        c.srcB = g_x2n + (size_t)bn * 128 * KD + (size_t)trow * KD + scol;
    }
    c.ldsf = &lds[0][0][0];
    c.ldst = t * 8;
    c.aoff0 = (wr * 64 + r) * 64 + s0 * 8;
    c.aoff1 = (wr * 64 + r) * 64 + s1 * 8;
    c.boff0 = (wc * 64 + r) * 64 + s0 * 8;
    c.boff1 = (wc * 64 + r) * 64 + s1 * 8;

    f32x4 acc[4][4] = {};

    // Prologue: stage tile 0 into buf0; drain; publish.
    stage_panel(c, true,  0);
    stage_panel(c, false, 1);
    c.srcA += 64; c.srcB += 64;
    asm volatile("s_waitcnt vmcnt(0)" ::: "memory");
    BARX();

    for (int it = 0; it < 7; ++it) {      // tiles 0..13 (stage 1..14)
        tile_body<0, true>(c, acc);
        tile_body<1, true>(c, acc);
    }
    tile_body<0, true>(c, acc);           // tile 14, stages 15
    tile_body<1, false>(c, acc);          // tile 15

    // Epilogue: C/D layout col = lane&15, row = (lane>>4)*4 + j.
    int cn = lane & 15, rq = (lane >> 4) * 4;
    int rbase = bm * 128 + wr * 64;
    int cbase = bn * 128 + wc * 64;
    #pragma unroll
    for (int mi = 0; mi < 4; ++mi)
        #pragma unroll
        for (int ni = 0; ni < 4; ++ni)
            #pragma unroll
            for (int j2 = 0; j2 < 4; ++j2)
                C[(size_t)(rbase + mi * 16 + rq + j2) * NROWS + cbase + ni * 16 + cn] =
                    acc[mi][ni][j2] * 20.0f;
}

extern "C" void kernel_launch(void* const* d_in, const int* in_sizes, int n_in,
                              void* d_out, int out_size, void* d_ws, size_t ws_size,
                              hipStream_t stream) {
    (void)in_sizes; (void)n_in; (void)d_ws; (void)ws_size; (void)out_size;
    const float* x1 = (const float*)d_in[0];
    const float* x2 = (const float*)d_in[1];
    float* out = (float*)d_out;

    norm_cast_kernel<<<2 * NROWS, 256, 0, stream>>>(x1, x2);
    gemm128_kernel<<<(NROWS / 128) * (NROWS / 128), 256, 0, stream>>>(out);
}

// Round 10
// 194.531 us; speedup vs baseline: 1.0357x; 1.0357x over previous
//
#include <hip/hip_runtime.h>
#include <hip/hip_bf16.h>

#define NROWS 8192
#define KD    1024

typedef __attribute__((ext_vector_type(8))) short bf16x8;
typedef __attribute__((ext_vector_type(4))) float f32x4;

__device__ unsigned short g_x1n[(size_t)NROWS * KD];   // row-major normalized x1
__device__ unsigned short g_x2p[(size_t)NROWS * KD];   // PACKED normalized x2 (B-fragment order)

__device__ __forceinline__ unsigned short f2bf(float f) {
    union { float f; unsigned u; } x; x.f = f;
    return (unsigned short)((x.u + 0x7fffu + ((x.u >> 16) & 1u)) >> 16);  // RNE
}

// x1 -> row-major; x2 -> packed: Bp[(m>>4)*32 + (k>>5)][lane = ((k>>3)&3)*16 + (m&15)][k&7]
// so that GEMM B-fragment lane l of (colgroup g, ktile kt) = Bp[(g*32+kt)*512 + l*8 .. +8].
__global__ __launch_bounds__(256) void norm_cast_kernel(const float* __restrict__ x1,
                                                        const float* __restrict__ x2) {
    int row = blockIdx.x;
    bool isA = row < NROWS;
    int m = isA ? row : row - NROWS;
    const float* src = (isA ? x1 : x2) + (size_t)m * KD;

    int t = threadIdx.x;
    float4 v = ((const float4*)src)[t];
    float s = v.x * v.x + v.y * v.y + v.z * v.z + v.w * v.w;
    #pragma unroll
    for (int off = 32; off > 0; off >>= 1) s += __shfl_down(s, off);

    __shared__ float red[4];
    if ((t & 63) == 0) red[t >> 6] = s;
    __syncthreads();
    float tot = red[0] + red[1] + red[2] + red[3];
    float inv = 1.0f / fmaxf(sqrtf(tot), 1e-8f);

    ushort4 o;
    o.x = f2bf(v.x * inv); o.y = f2bf(v.y * inv);
    o.z = f2bf(v.z * inv); o.w = f2bf(v.w * inv);

    if (isA) {
        ((ushort4*)(g_x1n + (size_t)m * KD))[t] = o;
    } else {
        int k = 4 * t;
        size_t off = ((size_t)((m >> 4) * 32 + (k >> 5))) * 512
                   + (size_t)((((k >> 3) & 3) * 16 + (m & 15)) * 8 + (k & 7));
        *(ushort4*)(g_x2p + off) = o;
    }
}

__device__ __forceinline__ void gload_lds16(const unsigned short* g, unsigned short* l) {
    __builtin_amdgcn_global_load_lds((const __attribute__((address_space(1))) void*)g,
                                     (__attribute__((address_space(3))) void*)l,
                                     16, 0, 0);
}

#define BARX() do { asm volatile("" ::: "memory"); __builtin_amdgcn_s_barrier(); \
                    asm volatile("" ::: "memory"); } while (0)
#define MFMA16(a, b, c) __builtin_amdgcn_mfma_f32_16x16x32_bf16((a), (b), (c), 0, 0, 0)

struct Ctx {
    const unsigned short* srcA;   // advancing per-lane A stage source (incl. trow*KD + scol)
    const unsigned short* srcB;   // advancing per-lane packed-B source (incl. lane*8)
    unsigned short* ldsf;         // A LDS base
    int ldst;                     // t*8
    int aoff0, aoff1;             // A ds_read offsets (kk 0/1), swizzled
    int wr;
};

// Stage full 256x64 A tile: 4 x global_load_lds(16B) per thread (512 threads).
__device__ __forceinline__ void stageA(Ctx& c, int buf) {
    unsigned short* dst = c.ldsf + buf * 16384 + c.ldst;
    #pragma unroll
    for (int i = 0; i < 4; ++i)
        gload_lds16(c.srcA + (size_t)(i * 64) * KD, dst + i * 4096);
    c.srcA += 64;
}

// Load 8 B-fragments (this wave's 64 cols x BK=64) from packed global into regs.
__device__ __forceinline__ void loadB(Ctx& c, bf16x8 (&Bv)[4][2]) {
    #pragma unroll
    for (int ci = 0; ci < 4; ++ci)
        #pragma unroll
        for (int kk = 0; kk < 2; ++kk)
            Bv[ci][kk] = *(const bf16x8*)(c.srcB + (ci * 32 + kk) * 512);
    c.srcB += 1024;
}

// One K-tile. Entry: A(T) published in buf, B(T) loads in flight (issued T-1 top).
// MODE 0 steady; MODE 1 last tile.
template<int BUF, int MODE>
__device__ __forceinline__ void tile_body(Ctx& c, f32x4 (&acc)[8][4],
                                          bf16x8 (&Bc)[4][2], bf16x8 (&Bn)[4][2]) {
    asm volatile("s_waitcnt vmcnt(0)" ::: "memory");   // B(T) landed (full-body distance)
    if (MODE == 0) {
        stageA(c, BUF ^ 1);                            // 4 gload_lds (oldest in vmcnt FIFO)
        __builtin_amdgcn_sched_barrier(0);
        loadB(c, Bn);                                  // 8 global loads for B(T+1)
        __builtin_amdgcn_sched_barrier(0);
    }

    const unsigned short* ab = c.ldsf + BUF * 16384 + c.wr * 8192;
    bf16x8 Af[4][2];

    // mi 0-3
    #pragma unroll
    for (int mi = 0; mi < 4; ++mi) {
        Af[mi][0] = *(const bf16x8*)(ab + mi * 1024 + c.aoff0);
        Af[mi][1] = *(const bf16x8*)(ab + mi * 1024 + c.aoff1);
    }
    __builtin_amdgcn_s_setprio(1);
    #pragma unroll
    for (int mi = 0; mi < 4; ++mi)
        #pragma unroll
        for (int ni = 0; ni < 4; ++ni) {
            acc[mi][ni] = MFMA16(Af[mi][0], Bc[ni][0], acc[mi][ni]);
            acc[mi][ni] = MFMA16(Af[mi][1], Bc[ni][1], acc[mi][ni]);
        }
    __builtin_amdgcn_s_setprio(0);

    // mi 4-7
    #pragma unroll
    for (int mi = 0; mi < 4; ++mi) {
        Af[mi][0] = *(const bf16x8*)(ab + (mi + 4) * 1024 + c.aoff0);
        Af[mi][1] = *(const bf16x8*)(ab + (mi + 4) * 1024 + c.aoff1);
    }
    __builtin_amdgcn_s_setprio(1);
    #pragma unroll
    for (int mi = 0; mi < 4; ++mi)
        #pragma unroll
        for (int ni = 0; ni < 4; ++ni) {
            acc[mi + 4][ni] = MFMA16(Af[mi][0], Bc[ni][0], acc[mi + 4][ni]);
            acc[mi + 4][ni] = MFMA16(Af[mi][1], Bc[ni][1], acc[mi + 4][ni]);
        }
    __builtin_amdgcn_s_setprio(0);

    if (MODE == 0) {
        // Retire the 4 A-stage loads (FIFO-oldest); B(T+1)'s 8 stay in flight.
        asm volatile("s_waitcnt vmcnt(8) lgkmcnt(0)" ::: "memory");
        BARX();                                        // publish A(T+1)
    }
}

// 256x256 tile, BK=64, 8 waves (2M x 4N). A via LDS dbuf (64 KiB); B direct
// from packed L2 band into reg double-buffer (never touches LDS).
__global__ __launch_bounds__(512, 2) void gemmbd_kernel(float* __restrict__ C) {
    __shared__ unsigned short Abuf[2][16384];   // 64 KiB

    // L2-rectangle XCD mapping (bijective), bn-band pinned per XCD (round 5: FETCH -63%).
    int bid = blockIdx.x;                 // 1024 blocks
    int xcd  = bid & 7;
    int idx  = bid >> 3;
    int rnd  = idx >> 5;
    int j    = idx & 31;
    int rect = rnd * 8 + xcd;
    int bm = (rect >> 2) * 4 + (j >> 3);
    int bn = (rect & 3) * 8 + (j & 7);

    int t = threadIdx.x;
    int lane = t & 63, wid = t >> 6;
    int wr = wid >> 2, wc = wid & 3;
    int r = lane & 15;
    int s0 = (lane >> 4) ^ (r & 7);       // swizzled 16B slot, kk=0
    int s1 = s0 ^ 4;                      // kk=1

    Ctx c;
    {
        int trow = t >> 3;                // 0..63
        int scol = ((t & 7) ^ (trow & 7)) * 8;   // inverse swizzle on global source
        c.srcA = g_x1n + (size_t)(bm * 256 + trow) * KD + scol;
    }
    c.srcB = g_x2p + (size_t)(bn * 16 + wc * 4) * 16384 + lane * 8;
    c.ldsf = &Abuf[0][0];
    c.ldst = t * 8;
    c.aoff0 = r * 64 + s0 * 8;
    c.aoff1 = r * 64 + s1 * 8;
    c.wr = wr;

    f32x4 acc[8][4] = {};
    bf16x8 B0r[4][2], B1r[4][2];

    // Prologue: stage A(0), load B(0); drain; publish.
    stageA(c, 0);
    loadB(c, B0r);
    asm volatile("s_waitcnt vmcnt(0)" ::: "memory");
    BARX();

    for (int it = 0; it < 7; ++it) {      // tiles 0..13 (stage/load 1..14)
        tile_body<0, 0>(c, acc, B0r, B1r);
        tile_body<1, 0>(c, acc, B1r, B0r);
    }
    tile_body<0, 0>(c, acc, B0r, B1r);    // tile 14, stages A(15), loads B(15)
    tile_body<1, 1>(c, acc, B1r, B0r);    // tile 15

    // Epilogue: C/D layout col = lane&15, row = (lane>>4)*4 + j.
    int cn = lane & 15, rq = (lane >> 4) * 4;
    int rbase = bm * 256 + wr * 128;
    int cbase = bn * 256 + wc * 64;
    #pragma unroll
    for (int mi = 0; mi < 8; ++mi)
        #pragma unroll
        for (int ni = 0; ni < 4; ++ni)
            #pragma unroll
            for (int j2 = 0; j2 < 4; ++j2)
                C[(size_t)(rbase + mi * 16 + rq + j2) * NROWS + cbase + ni * 16 + cn] =
                    acc[mi][ni][j2] * 20.0f;
}

extern "C" void kernel_launch(void* const* d_in, const int* in_sizes, int n_in,
                              void* d_out, int out_size, void* d_ws, size_t ws_size,
                              hipStream_t stream) {
    (void)in_sizes; (void)n_in; (void)d_ws; (void)ws_size; (void)out_size;
    const float* x1 = (const float*)d_in[0];
    const float* x2 = (const float*)d_in[1];
    float* out = (float*)d_out;

    norm_cast_kernel<<<2 * NROWS, 256, 0, stream>>>(x1, x2);
    gemmbd_kernel<<<(NROWS / 256) * (NROWS / 256), 512, 0, stream>>>(out);
}